// Round 9
// baseline (2165.279 us; speedup 1.0000x reference)
//
#include <hip/hip_runtime.h>

#define T_STEPS 512
#define BATCH   256
#define N_INP   128
#define N_HID   512
#define N_OUT   10

#define DT_C     0.042f
#define GAMMA_C  2.7f
#define EPS_C    4.7f

#define NWG        64      // 8 m-groups (32 rows) x 8 n-tiles (64 cols)
#define GROUP_WGS  8       // WGs per row-group
#define WG_THREADS 512     // 8 waves, 8-way K-split

typedef short          s16x8  __attribute__((ext_vector_type(8)));
typedef float          f32x16 __attribute__((ext_vector_type(16)));
typedef float          f32x4  __attribute__((ext_vector_type(4)));
typedef unsigned short u16x4  __attribute__((ext_vector_type(4)));
typedef unsigned long long u64;

__device__ inline unsigned short f2bf(float f) {
  union { float f; unsigned u; } v; v.f = f;
  unsigned r = v.u + 0x7fffu + ((v.u >> 16) & 1u);   // RNE
  return (unsigned short)(r >> 16);
}
__device__ inline float bf2f(unsigned short h) {
  union { unsigned u; float f; } v; v.u = ((unsigned)h) << 16;
  return v.f;
}

// ---- SLOW data plane: agent-scope write-through to IC. Proven R0/R4/R5/R7. ----
__device__ inline void pub8(unsigned short* p, u16x4 v) {
  union { u16x4 v; u64 q; } u; u.v = v;
  __hip_atomic_store((u64*)p, u.q, __ATOMIC_RELAXED, __HIP_MEMORY_SCOPE_AGENT);
}

// ---- FAST data plane (group co-resident on one XCD; gate hardware-validated
// R5/R7: engaged AND absmax-correct). sc0 stores commit at the group's shared
// L2; ack (vmcnt(0)) lives in the SAME asm block (R6 lesson).
// EMPIRICAL SAFETY RULE (9 rounds): only {agent-scope atomics, full
// __syncthreads, in-asm vmcnt over data} survive. sc0 SPINNING (R1/R2/R3/R6)
// and raw s_barrier substitutes (R8) both kill the container. Neither is used.
__device__ inline void pub_fast(unsigned short* pz, u16x4 vz,
                                unsigned short* py, u16x4 vy) {
  union { u16x4 v; u64 q; } uz, uy; uz.v = vz; uy.v = vy;
  asm volatile(
    "global_store_dwordx2 %0, %2, off sc0\n\t"
    "global_store_dwordx2 %1, %3, off sc0\n\t"
    "s_waitcnt vmcnt(0)"
    :: "v"(pz), "v"(py), "v"(uz.q), "v"(uy.q) : "memory");
}

// 8 coherent 16B loads + waitcnt fused in ONE asm block (R6 lesson). CP picks
// the read point: "sc0 sc1" = IC (cross-XCD), "sc0" = XCD L2.
#define STATE_LD8_CP(HB, HP, CP)                                             \
  asm volatile(                                                              \
    "global_load_dwordx4 %0, %8, off " CP "\n\t"                             \
    "global_load_dwordx4 %1, %8, off offset:32 " CP "\n\t"                   \
    "global_load_dwordx4 %2, %8, off offset:64 " CP "\n\t"                   \
    "global_load_dwordx4 %3, %8, off offset:96 " CP "\n\t"                   \
    "global_load_dwordx4 %4, %8, off offset:128 " CP "\n\t"                  \
    "global_load_dwordx4 %5, %8, off offset:160 " CP "\n\t"                  \
    "global_load_dwordx4 %6, %8, off offset:192 " CP "\n\t"                  \
    "global_load_dwordx4 %7, %8, off offset:224 " CP "\n\t"                  \
    "s_waitcnt vmcnt(0)"                                                     \
    : "=&v"(HB[0]), "=&v"(HB[1]), "=&v"(HB[2]), "=&v"(HB[3]),                \
      "=&v"(HB[4]), "=&v"(HB[5]), "=&v"(HB[6]), "=&v"(HB[7])                 \
    : "v"(HP)                                                                \
    : "memory")

// HW_REG_XCC_ID = hwreg id 20 (gfx940+), offset 0, size 4.
#define XCC_ID_IMM ((20) | ((4 - 1) << 11))

// Persistent recurrent kernel. Control plane: per-WG step counters (64B-strided
// lines). tid0 adds 1 after the publish-acked join __syncthreads (R7-proven
// discipline). Rendezvous is PER-WAVE: wave ks consumes state cols
// [128*(ks&3), 128*(ks&3)+128), produced by exactly WGs {2*(ks&3), 2*(ks&3)+1}
// — so each wave polls only its 2 producers (R0-proven ballot pattern) and
// starts its state loads + MFMAs immediately, overlapping the wait for slower
// producers with compute in the other waves. WAR on the 2-deep Hbf buffer is
// preserved COLLECTIVELY: the 8 waves' pairs cover all 8 WGs, and all polls
// precede the sC __syncthreads that precedes the publish.
// Hbf: double-buffered published state, bf16 [2][256][1024]; col c<512 = hz[c]
//      (W row 128+c), col 512+c = hy[c] (W row 640+c).
__global__ __launch_bounds__(WG_THREADS, 2) void cornn_kernel(
    const float* __restrict__ x, const float* __restrict__ W,
    const float* __restrict__ bias, unsigned short* __restrict__ Hbf,
    float* __restrict__ Hy32, unsigned* __restrict__ flags_ws) {
  const int tid   = threadIdx.x;
  const int lane  = tid & 63;
  const int ks    = tid >> 6;        // wave id 0..7 (8-way K-split)
  const int half  = lane >> 5;       // A/B frag k-half
  const int half8 = half << 3;
  const int lcol  = lane & 31;
  const int mi    = blockIdx.x & 7;  // row group
  const int ni    = blockIdx.x >> 3; // 64-col tile, 0..7
  const int rowA  = (mi << 5) + lcol;

  // per-WG counter: dword offset mi*128 + ni*16 (64B per WG line)
  unsigned* gbase = flags_ws + mi * 128;

  __shared__ float sC[8][2048];   // K-split partials (32 rows x 64 cols), 64 KB
  __shared__ float sB[64];

  // ---- stage W in registers: state 8 chunks/wave x 2 col-tiles (hi+lo),
  //      x 1 chunk/wave x 2 col-tiles (hi+lo) ----
  s16x8 whi0[8], wlo0[8], whi1[8], wlo1[8];
  s16x8 wxhi0, wxlo0, wxhi1, wxlo1;
  const int c0t = (ni << 6) + lcol;      // col tile 0
  #pragma unroll
  for (int i = 0; i < 8; ++i) {
    const int wr = 128 + (ks << 7) + i * 16 + half8;
    const float* wp0 = W + (size_t)wr * N_HID + c0t;
    s16x8 hi0, lo0, hi1, lo1;
    #pragma unroll
    for (int j = 0; j < 8; ++j) {
      float f0 = wp0[(size_t)j * N_HID];
      float f1 = wp0[(size_t)j * N_HID + 32];
      unsigned short h0 = f2bf(f0), h1 = f2bf(f1);
      hi0[j] = (short)h0;  lo0[j] = (short)f2bf(f0 - bf2f(h0));
      hi1[j] = (short)h1;  lo1[j] = (short)f2bf(f1 - bf2f(h1));
    }
    whi0[i] = hi0; wlo0[i] = lo0; whi1[i] = hi1; wlo1[i] = lo1;
  }
  {
    const int wr = (ks << 4) + half8;    // x chunk ks: k = ks*16
    const float* wp0 = W + (size_t)wr * N_HID + c0t;
    s16x8 hi0, lo0, hi1, lo1;
    #pragma unroll
    for (int j = 0; j < 8; ++j) {
      float f0 = wp0[(size_t)j * N_HID];
      float f1 = wp0[(size_t)j * N_HID + 32];
      unsigned short h0 = f2bf(f0), h1 = f2bf(f1);
      hi0[j] = (short)h0;  lo0[j] = (short)f2bf(f0 - bf2f(h0));
      hi1[j] = (short)h1;  lo1[j] = (short)f2bf(f1 - bf2f(h1));
    }
    wxhi0 = hi0; wxlo0 = lo0; wxhi1 = hi1; wxlo1 = lo1;
  }
  if (tid < 64) sB[tid] = bias[(ni << 6) + tid];

  // ---- per-thread fp32 state (4 cols each; 512 thr x 4 = 32 rows x 64 cols) ----
  const int e0   = tid << 2;
  const int rowL = e0 >> 6, c0 = e0 & 63;
  const int rowG = (mi << 5) + rowL;
  const int colG = (ni << 6) + c0;
  f32x4 hz = {0.f, 0.f, 0.f, 0.f};
  f32x4 hy = {0.f, 0.f, 0.f, 0.f};

  const unsigned short* hb2[2];
  hb2[0] = Hbf + (size_t)rowA * 1024 + (ks << 7) + half8;
  hb2[1] = hb2[0] + 256 * 1024;
  unsigned short* wz[2];
  unsigned short* wy[2];
  wz[0] = Hbf + (size_t)rowG * 1024 + colG;       wz[1] = wz[0] + 256 * 1024;
  wy[0] = wz[0] + 512;                            wy[1] = wz[1] + 512;

  // ---- one-time XCD topology detection, PLAUSIBILITY-GATED (hardware-
  // validated R5/R7: engaged AND absmax-correct). Gates DATA plane only. ----
  const unsigned myxcc = __builtin_amdgcn_s_getreg(XCC_ID_IMM) & 0xfu;
  unsigned* xslots = flags_ws + 1024;   // 64 dwords at byte 4096 (zeroed)
  if (tid == 0)
    __hip_atomic_store(&xslots[(mi << 3) | ni], myxcc + 1u,
                       __ATOMIC_RELAXED, __HIP_MEMORY_SCOPE_AGENT);
  bool fastp;
  {
    unsigned gmn, gmx, amn, amx;
    for (;;) {
      gmn = amn = 0xffffffffu; gmx = amx = 0u;
      for (int j = 0; j < 64; ++j) {
        unsigned v = __hip_atomic_load(&xslots[j], __ATOMIC_RELAXED, __HIP_MEMORY_SCOPE_AGENT);
        amn = v < amn ? v : amn;  amx = v > amx ? v : amx;
        if ((j >> 3) == mi) { gmn = v < gmn ? v : gmn;  gmx = v > gmx ? v : gmx; }
      }
      if (amn != 0u) break;     // all 64 WGs have reported
      __builtin_amdgcn_s_sleep(16);
    }
    fastp = (gmn == gmx) && (amn != amx);
  }

  __syncthreads();   // sB visible (one-time; outside the step loop)

  // ---- 2-deep x register pipeline (R4 lesson): x(t+1) issued at loop top;
  // its drain lands inside the poll/STATE_LD8 wait windows, off the chain. ----
  const float* xbase = x + (size_t)rowA * N_INP + (ks << 4) + half8;
  f32x4 xr0 = *reinterpret_cast<const f32x4*>(xbase);
  f32x4 xr1 = *reinterpret_cast<const f32x4*>(xbase + 4);

  // this wave's two producers (same pair for hz (ks<4) and hy (ks>=4) parts)
  const int prod = ((ks & 3) << 1) + (lane & 1);   // valid 0..7 for all lanes

  for (int t = 0; t < T_STEPS; ++t) {
    const float* xpn =
        xbase + (size_t)((t + 1 < T_STEPS) ? t + 1 : t) * (BATCH * N_INP);
    f32x4 xn0 = *reinterpret_cast<const f32x4*>(xpn);
    f32x4 xn1 = *reinterpret_cast<const f32x4*>(xpn + 4);
    __builtin_amdgcn_sched_barrier(0);

    f32x16 acc0 = {};
    f32x16 acc1 = {};

    // ---- x-part (no state dep): alternate acc0/acc1 to break MFMA chains ----
    {
      s16x8 ahi, alo;
      #pragma unroll
      for (int j = 0; j < 4; ++j) {
        float f0 = xr0[j], f1 = xr1[j];
        unsigned short h0 = f2bf(f0), h1 = f2bf(f1);
        ahi[j]     = (short)h0;  ahi[j + 4] = (short)h1;
        alo[j]     = (short)f2bf(f0 - bf2f(h0));
        alo[j + 4] = (short)f2bf(f1 - bf2f(h1));
      }
      acc0 = __builtin_amdgcn_mfma_f32_32x32x16_bf16(ahi, wxhi0, acc0, 0, 0, 0);
      acc1 = __builtin_amdgcn_mfma_f32_32x32x16_bf16(ahi, wxhi1, acc1, 0, 0, 0);
      acc0 = __builtin_amdgcn_mfma_f32_32x32x16_bf16(ahi, wxlo0, acc0, 0, 0, 0);
      acc1 = __builtin_amdgcn_mfma_f32_32x32x16_bf16(ahi, wxlo1, acc1, 0, 0, 0);
      acc0 = __builtin_amdgcn_mfma_f32_32x32x16_bf16(alo, wxhi0, acc0, 0, 0, 0);
      acc1 = __builtin_amdgcn_mfma_f32_32x32x16_bf16(alo, wxhi1, acc1, 0, 0, 0);
    }

    if (t > 0) {
      // ---- per-wave rendezvous on this wave's TWO producers only (R0-proven
      // ballot pattern, agent scope). counter_p >= t <=> WG p completed step
      // t-1 (publish acked before its tid0 add). Own WG exempt. Waves with
      // faster producers proceed immediately -> their state compute overlaps
      // the slowest producer's tail. ----
      const unsigned tgt = (unsigned)t;
      for (;;) {
        unsigned v = __hip_atomic_load(&gbase[prod * 16], __ATOMIC_RELAXED, __HIP_MEMORY_SCOPE_AGENT);
        if (__ballot((lane >= 2) | (prod == ni) | (v >= tgt)) == ~0ull) break;
        __builtin_amdgcn_s_sleep(1);
      }

      // ---- state: 8 pipelined coherent 16B loads, ONE round-trip ----
      const unsigned short* hp = hb2[t & 1];
      f32x4 hbuf[8];
      if (fastp) { STATE_LD8_CP(hbuf, hp, "sc0"); }
      else       { STATE_LD8_CP(hbuf, hp, "sc0 sc1"); }

      #pragma unroll
      for (int i = 0; i < 8; ++i) {
        union { f32x4 f; s16x8 s; } u; u.f = hbuf[i];
        acc0 = __builtin_amdgcn_mfma_f32_32x32x16_bf16(u.s, whi0[i], acc0, 0, 0, 0);
        acc1 = __builtin_amdgcn_mfma_f32_32x32x16_bf16(u.s, whi1[i], acc1, 0, 0, 0);
        acc0 = __builtin_amdgcn_mfma_f32_32x32x16_bf16(u.s, wlo0[i], acc0, 0, 0, 0);
        acc1 = __builtin_amdgcn_mfma_f32_32x32x16_bf16(u.s, wlo1[i], acc1, 0, 0, 0);
      }
    }

    // ---- K-split partials (C/D layout: col=lane&31, row=(r&3)+8*(r>>2)+4*half) ----
    #pragma unroll
    for (int r = 0; r < 16; ++r) {
      const int rowL_r = (r & 3) + ((r >> 2) << 3) + (half << 2);
      sC[ks][rowL_r * 64 + lcol]      = acc0[r];
      sC[ks][rowL_r * 64 + 32 + lcol] = acc1[r];
    }
    __syncthreads();   // full drain + join (proven); orders ALL polls before publish

    // ---- reduce (8-way) + tanh + state update + publish ----
    {
      f32x4 s = *reinterpret_cast<f32x4*>(&sC[0][e0]);
      #pragma unroll
      for (int w = 1; w < 8; ++w) s += *reinterpret_cast<f32x4*>(&sC[w][e0]);
      u16x4 pz, py;
      #pragma unroll
      for (int j = 0; j < 4; ++j) {
        float pre = tanhf(s[j] + sB[c0 + j]);
        float z = hz[j] + DT_C * (pre - GAMMA_C * hy[j] - EPS_C * hz[j]);
        float y = hy[j] + DT_C * z;
        hz[j] = z; hy[j] = y;
        pz[j] = f2bf(z); py[j] = f2bf(y);
      }
      const int wb = (t & 1) ^ 1;
      if (fastp) {
        pub_fast(wz[wb], pz, wy[wb], py);   // sc0 stores + in-asm L2 ack
      } else {
        pub8(wz[wb], pz); pub8(wy[wb], py); // IC write-through (proven)
      }
    }
    __syncthreads();   // join + vmcnt drain: all publishes acked before the add
    if (tid == 0)
      __hip_atomic_fetch_add(&gbase[ni * 16], 1u,
                             __ATOMIC_RELAXED, __HIP_MEMORY_SCOPE_AGENT);
    xr0 = xn0; xr1 = xn1;
  }

  if (Hy32 != nullptr)
    *reinterpret_cast<f32x4*>(Hy32 + (size_t)rowG * 512 + colG) = hy;
}

// out[b][c] = sum_k hy[b][k] * Wout[k][c] + bout[c]
__global__ void cornn_out_kernel(const float* __restrict__ Hy32,
                                 const unsigned short* __restrict__ HbfFinal,
                                 const float* __restrict__ Wout,
                                 const float* __restrict__ bout,
                                 float* __restrict__ out) {
  const int b = blockIdx.x;
  const int lane = threadIdx.x;   // 64 threads
  float a[N_OUT];
  #pragma unroll
  for (int c = 0; c < N_OUT; ++c) a[c] = 0.f;
  #pragma unroll
  for (int j = 0; j < 8; ++j) {
    const int k = lane + (j << 6);
    const float h = Hy32 ? Hy32[(size_t)b * N_HID + k]
                         : bf2f(HbfFinal[(size_t)b * 1024 + 512 + k]);
    const float* wr = Wout + (size_t)k * N_OUT;
    #pragma unroll
    for (int c = 0; c < N_OUT; ++c) a[c] += h * wr[c];
  }
  #pragma unroll
  for (int c = 0; c < N_OUT; ++c) {
    float v = a[c];
    for (int off = 32; off > 0; off >>= 1) v += __shfl_down(v, off, 64);
    if (lane == 0) out[(size_t)b * N_OUT + c] = v + bout[c];
  }
}

extern "C" void kernel_launch(void* const* d_in, const int* in_sizes, int n_in,
                              void* d_out, int out_size, void* d_ws, size_t ws_size,
                              hipStream_t stream) {
  (void)in_sizes; (void)n_in; (void)out_size;
  const float* x    = (const float*)d_in[0];
  const float* W    = (const float*)d_in[1];
  const float* bias = (const float*)d_in[2];
  const float* Wout = (const float*)d_in[3];
  const float* bout = (const float*)d_in[4];

  char* ws = (char*)d_ws;
  unsigned*       flags = (unsigned*)ws;                      // 8 KiB counter+slot area
  unsigned short* Hbf   = (unsigned short*)(ws + 8192);       // 2 x 256 x 1024 bf16 = 1 MiB
  float*          Hy32  = (float*)(ws + 8192 + (size_t)2 * 256 * 1024 * 2);
  const size_t needed = 8192 + (size_t)2 * 256 * 1024 * 2 + (size_t)256 * 512 * 4;
  float* hyPtr = (ws_size >= needed) ? Hy32 : nullptr;

  hipMemsetAsync(flags, 0, 8192, stream);   // counters + xcd slots = 0

  cornn_kernel<<<dim3(NWG), dim3(WG_THREADS), 0, stream>>>(x, W, bias, Hbf, hyPtr, flags);

  cornn_out_kernel<<<dim3(BATCH), dim3(64), 0, stream>>>(hyPtr, Hbf, Wout, bout,
                                                         (float*)d_out);
}